// Round 16
// baseline (304.299 us; speedup 1.0000x reference)
//
#include <hip/hip_runtime.h>

typedef _Float16 f16;
typedef _Float16 f16x8 __attribute__((ext_vector_type(8)));
typedef _Float16 f16x4 __attribute__((ext_vector_type(4)));
typedef float f32x4 __attribute__((ext_vector_type(4)));

#define MFMA16(a, b, c) __builtin_amdgcn_mfma_f32_16x16x32_f16(a, b, c, 0, 0, 0)
#define MFMA16K16(a, b, c) __builtin_amdgcn_mfma_f32_16x16x16f16(a, b, c, 0, 0, 0)

// =====================================================================
// k_mt3: all three M_h = Wq_h^T Wk_h products in ONE launch.
// grid (16 heads, 68 tiles): y<16 -> hv (H=256), y<52 -> ce (H=384),
// else sce (H=256). Stored K-blocked: MT[h][e>>5][f][e&31].
// =====================================================================
__global__ __launch_bounds__(256) void k_mt3(const float* __restrict__ Wq_hv,
                                             const float* __restrict__ Wk_hv,
                                             f16* __restrict__ mt_hv,
                                             const float* __restrict__ Wq_ce,
                                             const float* __restrict__ Wk_ce,
                                             f16* __restrict__ mt_ce,
                                             const float* __restrict__ Wq_sce,
                                             const float* __restrict__ Wk_sce,
                                             f16* __restrict__ mt_sce) {
    const int y = blockIdx.y;
    const float *Wq, *Wk;
    f16* MT;
    int H, ty;
    if (y < 16)      { Wq = Wq_hv;  Wk = Wk_hv;  MT = mt_hv;  H = 256; ty = y; }
    else if (y < 52) { Wq = Wq_ce;  Wk = Wk_ce;  MT = mt_ce;  H = 384; ty = y - 16; }
    else             { Wq = Wq_sce; Wk = Wk_sce; MT = mt_sce; H = 256; ty = y - 52; }

    const int h = blockIdx.x;
    const int ntile = H >> 6;
    const int nkk = H >> 5;
    const int frow = (ty / ntile) * 64;
    const int ecol = (ty % ntile) * 64;
    const int t = threadIdx.x;
    const int lane = t & 63;
    const int w = t >> 6;
    const int wr = w >> 1, wc = w & 1;

    __shared__ __align__(16) f16 As[64][40];
    __shared__ __align__(16) f16 Ks[64][40];

    f32x4 acc[2][2] = {};
    const int d = t >> 3;
    const int e8 = (t & 7) * 8;

    for (int kk = 0; kk < nkk; ++kk) {
        const float* gq = Wq + (size_t)(h * H + kk * 32 + d) * H + ecol + e8;
        const float* gk = Wk + (size_t)(h * H + kk * 32 + d) * H + frow + e8;
        float q[8], k[8];
#pragma unroll
        for (int i = 0; i < 8; ++i) { q[i] = gq[i]; k[i] = gk[i]; }
        __syncthreads();
#pragma unroll
        for (int i = 0; i < 8; ++i) { As[e8 + i][d] = (f16)q[i]; Ks[e8 + i][d] = (f16)k[i]; }
        __syncthreads();
        f16x8 a[2], b[2];
#pragma unroll
        for (int rt = 0; rt < 2; ++rt)
            a[rt] = *(const f16x8*)&Ks[wr * 32 + rt * 16 + (lane & 15)][(lane >> 4) * 8];
#pragma unroll
        for (int nt = 0; nt < 2; ++nt)
            b[nt] = *(const f16x8*)&As[wc * 32 + nt * 16 + (lane & 15)][(lane >> 4) * 8];
#pragma unroll
        for (int rt = 0; rt < 2; ++rt)
#pragma unroll
            for (int nt = 0; nt < 2; ++nt)
                acc[rt][nt] = MFMA16(a[rt], b[nt], acc[rt][nt]);
    }
#pragma unroll
    for (int rt = 0; rt < 2; ++rt)
#pragma unroll
        for (int nt = 0; nt < 2; ++nt)
#pragma unroll
            for (int j = 0; j < 4; ++j) {
                int f = frow + wr * 32 + rt * 16 + (lane >> 4) * 4 + j;
                int e = ecol + wc * 32 + nt * 16 + (lane & 15);
                MT[(((size_t)h * nkk + (e >> 5)) * H + f) * 32 + (e & 31)] = (f16)acc[rt][nt][j];
            }
}

// =====================================================================
// k_lin: out[r][j] = sum_d in[r][d]*W[j][d] + b[j], J=256, 4 rows/block.
// =====================================================================
__global__ __launch_bounds__(256) void k_lin(const float* __restrict__ in,
                                             const float* __restrict__ W,
                                             const float* __restrict__ bias,
                                             float* __restrict__ out, int K) {
    const int t = threadIdx.x;
    const int r0 = blockIdx.x * 4;
    __shared__ float ins[4][384];
    __shared__ float Ws[256][33];
#pragma unroll
    for (int r = 0; r < 4; ++r)
        for (int off = t; off < K; off += 256)
            ins[r][off] = in[(size_t)(r0 + r) * K + off];
    float acc[4] = {};
    for (int d0 = 0; d0 < K; d0 += 32) {
        __syncthreads();
        for (int i = t; i < 256 * 32; i += 256) {
            int j = i >> 5, dd = i & 31;
            Ws[j][dd] = W[(size_t)j * K + d0 + dd];
        }
        __syncthreads();
#pragma unroll 8
        for (int dd = 0; dd < 32; ++dd) {
            float wv = Ws[t][dd];
#pragma unroll
            for (int r = 0; r < 4; ++r) acc[r] += wv * ins[r][d0 + dd];
        }
    }
    float bv = bias[t];
#pragma unroll
    for (int r = 0; r < 4; ++r) out[(size_t)(r0 + r) * 256 + t] = acc[r] + bv;
}

// =====================================================================
// k_small_int v5: 8 pos-groups/block (32 X-rows), grid (32,16) = 512
// blocks (2/CU). Phase 2: waves 0,1 each own one 16-row S-tile.
// =====================================================================
__global__ __launch_bounds__(256) void k_small_int(const float* __restrict__ X,
                                                   const f16* __restrict__ MT,
                                                   float* __restrict__ wpart) {
    const int t = threadIdx.x;
    const int lane = t & 63;
    const int w = t >> 6;
    const int g = lane >> 4;
    const int l15 = lane & 15;
    const int pos0 = blockIdx.x * 8;
    const int h = blockIdx.y;

    __shared__ __align__(16) f16 Xs[32][264];
    __shared__ __align__(16) f16 Ts[32][264];

    {
        int row = t >> 3, d0 = (t & 7) * 32;
        int s = row & 3, p = row >> 2;
        const float* gx = X + (size_t)(s * 256 + pos0 + p) * 256 + d0;
#pragma unroll
        for (int i = 0; i < 32; i += 8) {
            float4 v0 = *(const float4*)(gx + i);
            float4 v1 = *(const float4*)(gx + i + 4);
            f16x8 o;
            o[0] = (f16)v0.x; o[1] = (f16)v0.y; o[2] = (f16)v0.z; o[3] = (f16)v0.w;
            o[4] = (f16)v1.x; o[5] = (f16)v1.y; o[6] = (f16)v1.z; o[7] = (f16)v1.w;
            *(f16x8*)&Xs[row][d0 + i] = o;
        }
    }
    __syncthreads();

    const f16* mh = MT + (size_t)h * 8 * 256 * 32;
    const int fb = w * 64 + l15;
    f32x4 acc[2][4] = {};
    f16x8 bq[4], bn[4];
#pragma unroll
    for (int nt = 0; nt < 4; ++nt)
        bq[nt] = *(const f16x8*)(mh + (size_t)(fb + nt * 16) * 32 + g * 8);
#pragma unroll
    for (int kk = 0; kk < 8; ++kk) {
        if (kk < 7) {
#pragma unroll
            for (int nt = 0; nt < 4; ++nt)
                bn[nt] = *(const f16x8*)(mh + ((size_t)(kk + 1) * 256 + fb + nt * 16) * 32 + g * 8);
        }
        f16x8 a[2];
#pragma unroll
        for (int mt = 0; mt < 2; ++mt)
            a[mt] = *(const f16x8*)&Xs[mt * 16 + l15][kk * 32 + g * 8];
#pragma unroll
        for (int mt = 0; mt < 2; ++mt)
#pragma unroll
            for (int nt = 0; nt < 4; ++nt)
                acc[mt][nt] = MFMA16(a[mt], bq[nt], acc[mt][nt]);
#pragma unroll
        for (int nt = 0; nt < 4; ++nt) bq[nt] = bn[nt];
    }
#pragma unroll
    for (int mt = 0; mt < 2; ++mt)
#pragma unroll
        for (int nt = 0; nt < 4; ++nt)
#pragma unroll
            for (int j = 0; j < 4; ++j)
                Ts[mt * 16 + g * 4 + j][w * 64 + nt * 16 + l15] = (f16)acc[mt][nt][j];
    __syncthreads();

    if (w < 2) {
        f32x4 sacc = {};
#pragma unroll
        for (int ks = 0; ks < 8; ++ks) {
            f16x8 a = *(const f16x8*)&Ts[w * 16 + l15][ks * 32 + g * 8];
            f16x8 b = *(const f16x8*)&Xs[w * 16 + l15][ks * 32 + g * 8];
            sacc = MFMA16(a, b, sacc);
        }
        if ((l15 >> 2) == g) {
            const float scale = 1.0f / 16.0f; // 1/sqrt(256)
            float add = 0.f;
#pragma unroll
            for (int j = 0; j < 4; ++j) {
                float v = sacc[j] * scale;
                float m = v;
                m = fmaxf(m, __shfl_xor(m, 1));
                m = fmaxf(m, __shfl_xor(m, 2));
                float e = expf(v - m);
                float s2 = e;
                s2 += __shfl_xor(s2, 1);
                s2 += __shfl_xor(s2, 2);
                add += e / s2;
            }
            int pg = pos0 + w * 4 + g;
            wpart[((size_t)h * 256 + pg) * 4 + (l15 & 3)] = add;
        }
    }
}

// =====================================================================
// k_small_fin: sum 16 head-partials -> /64 -> softmax(4) -> pool states.
// =====================================================================
__global__ __launch_bounds__(256) void k_small_fin(const float* __restrict__ wpart,
                                                   const float* __restrict__ X,
                                                   float* __restrict__ out_int,
                                                   float* __restrict__ out_w) {
    const int pos = blockIdx.x, t = threadIdx.x;
    __shared__ float red[64];
    __shared__ float ws[4];
    if (t < 64) red[t] = wpart[((size_t)(t >> 2) * 256 + pos) * 4 + (t & 3)];
    __syncthreads();
    if (t == 0) {
        float v[4];
#pragma unroll
        for (int s = 0; s < 4; ++s) {
            float x = 0.f;
            for (int hh = 0; hh < 16; ++hh) x += red[hh * 4 + s];
            v[s] = x * (1.0f / 64.0f);
        }
        float m = fmaxf(fmaxf(v[0], v[1]), fmaxf(v[2], v[3]));
        float sum = 0.f;
#pragma unroll
        for (int s = 0; s < 4; ++s) { v[s] = expf(v[s] - m); sum += v[s]; }
#pragma unroll
        for (int s = 0; s < 4; ++s) ws[s] = v[s] / sum;
    }
    __syncthreads();
    if (t < 4) out_w[pos * 4 + t] = ws[t];
    float v = 0.f;
#pragma unroll
    for (int s = 0; s < 4; ++s) v += ws[s] * X[(size_t)(s * 256 + pos) * 256 + t];
    out_int[(size_t)pos * 256 + t] = v;
}

// =====================================================================
// k_ce_int v15: BARRIER-FREE per-wave-head. 64 tokens/block, grid 512.
// Each wave owns a whole head (8 waves x 2 iters = 16 heads), e' in 12
// chunks of 32 rows: phase-1 acc[2][4] -> cast -> phase-2 accumulates
// into persistent S2[2][2][2] (full S in regs). Softmax per-wave,
// direct global write. ZERO barriers after X staging, no merge LDS.
// VGPR ~120 <= 128 (no allocator fight). LDS 49152 -> 2 blk/CU,
// 4 waves/SIMD. acc_out: [16][1024][2][32].
// =====================================================================
__global__ __launch_bounds__(512) void k_ce_int(const float* __restrict__ Xg32,
                                                const f16* __restrict__ MT,
                                                float* __restrict__ acc_out) {
    const int t = threadIdx.x;
    const int lane = t & 63;
    const int w = t >> 6;       // 0..7
    const int g = lane >> 4;
    const int l15 = lane & 15;
    const int bg = blockIdx.x;  // 0..511, 2 b's each

    extern __shared__ __align__(16) char smem[];

    // ---- stage X (64 x 384), f32 -> f16, source-swizzled, linear LDS ----
    {
        const float* xg = Xg32 + (size_t)bg * 64 * 384;
#pragma unroll
        for (int p = 0; p < 6; ++p) {
            int idx = p * 512 + t;          // 3072 16B units
            int row = idx / 48, s = idx - row * 48;
            int c = s ^ (row & 7);
            const float* src = xg + row * 384 + c * 8;
            float4 v0 = *(const float4*)src;
            float4 v1 = *(const float4*)(src + 4);
            f16x8 o;
            o[0] = (f16)v0.x; o[1] = (f16)v0.y; o[2] = (f16)v0.z; o[3] = (f16)v0.w;
            o[4] = (f16)v1.x; o[5] = (f16)v1.y; o[6] = (f16)v1.z; o[7] = (f16)v1.w;
            *(f16x8*)(smem + idx * 16) = o;
        }
    }
    __syncthreads();   // the ONLY barrier

    const float scale = 0.051031036307982884f; // 1/sqrt(384)

    for (int h2 = 0; h2 < 2; ++h2) {
        const int h = h2 * 8 + w;               // this wave's head
        const f16* mh = MT + (size_t)h * 12 * 12288;  // [12 kk][384][32]

        f32x4 S2[2][2][2] = {};  // [b][it][lt] persistent across chunks

        // depth-1 ping-pong A prefetch over flattened step = c*12+kk
        f16x8 A[2][2];
#pragma unroll
        for (int ft = 0; ft < 2; ++ft)
            A[0][ft] = *(const f16x8*)(mh + (size_t)(0 * 32 + ft * 16 + l15) * 32 + g * 8);

        for (int c = 0; c < 12; ++c) {
            // ---- phase 1: Tt_chunk = M[:,chunk]^T @ X (32 e' rows) ----
            f32x4 acc[2][4] = {};
#pragma unroll
            for (int kk = 0; kk < 12; ++kk) {
                const int step = c * 12 + kk;
                {   // prefetch step+1
                    int ns = step + 1;
                    int nc = ns / 12, nk = ns - nc * 12;
                    if (nc > 11) { nc = 11; nk = 11; }
#pragma unroll
                    for (int ft = 0; ft < 2; ++ft)
                        A[(step + 1) & 1][ft] =
                            *(const f16x8*)(mh + (size_t)nk * 12288 +
                                            (size_t)(nc * 32 + ft * 16 + l15) * 32 + g * 8);
                }
                f16x8 xb[4];
#pragma unroll
                for (int mt = 0; mt < 4; ++mt) {
                    int row = mt * 16 + l15;
                    int ch = kk * 4 + g;
                    xb[mt] = *(const f16x8*)(smem + row * 768 + ((ch ^ (row & 7)) << 4));
                }
                __builtin_amdgcn_s_setprio(1);
#pragma unroll
                for (int ft = 0; ft < 2; ++ft)
#pragma unroll
                    for (int mt = 0; mt < 4; ++mt)
                        acc[ft][mt] = MFMA16(A[step & 1][ft], xb[mt], acc[ft][mt]);
                __builtin_amdgcn_s_setprio(0);
            }

            // ---- cast chunk Tt -> f16 B-frags (layout == K16 B-frag) ----
            f16x4 bf[2][4];
#pragma unroll
            for (int ft = 0; ft < 2; ++ft)
#pragma unroll
                for (int mt = 0; mt < 4; ++mt) {
                    f32x4 v = acc[ft][mt];
                    f16x4 o;
                    o[0] = (f16)v[0]; o[1] = (f16)v[1]; o[2] = (f16)v[2]; o[3] = (f16)v[3];
                    bf[ft][mt] = o;
                }

            // ---- phase 2: accumulate S over this chunk's 32 e' ----
#pragma unroll
            for (int b = 0; b < 2; ++b)
#pragma unroll
                for (int ks = 0; ks < 2; ++ks)
#pragma unroll
                    for (int it = 0; it < 2; ++it) {
                        int row = b * 32 + it * 16 + l15;
                        int ch = c * 4 + ks * 2 + (g >> 1);
                        f16x4 av = *(const f16x4*)(smem + row * 768 +
                                                   ((ch ^ (row & 7)) << 4) + 8 * (g & 1));
#pragma unroll
                        for (int lt = 0; lt < 2; ++lt)
                            S2[b][it][lt] = MFMA16K16(av, bf[ks][2 * b + lt], S2[b][it][lt]);
                    }
        }

        // ---- softmax + column sums per (b, it), direct global write ----
#pragma unroll
        for (int b = 0; b < 2; ++b)
#pragma unroll
            for (int it = 0; it < 2; ++it) {
                f32x4 sum0 = S2[b][it][0];
                f32x4 sum1 = S2[b][it][1];
                float cs0 = 0.f, cs1 = 0.f;
#pragma unroll
                for (int j = 0; j < 4; ++j) {
                    float v0 = sum0[j] * scale, v1 = sum1[j] * scale;
                    float m = fmaxf(v0, v1);
                    m = fmaxf(m, __shfl_xor(m, 1));
                    m = fmaxf(m, __shfl_xor(m, 2));
                    m = fmaxf(m, __shfl_xor(m, 4));
                    m = fmaxf(m, __shfl_xor(m, 8));
                    float e0 = __expf(v0 - m), e1 = __expf(v1 - m);
                    float s = e0 + e1;
                    s += __shfl_xor(s, 1);
                    s += __shfl_xor(s, 2);
                    s += __shfl_xor(s, 4);
                    s += __shfl_xor(s, 8);
                    float inv = 1.f / s;
                    cs0 += e0 * inv;
                    cs1 += e1 * inv;
                }
                cs0 += __shfl_xor(cs0, 16); cs0 += __shfl_xor(cs0, 32);
                cs1 += __shfl_xor(cs1, 16); cs1 += __shfl_xor(cs1, 32);
                if (lane < 16) {
                    float* o = acc_out + (((size_t)h * 1024 + bg * 2 + b) * 2 + it) * 32;
                    o[l15] = cs0;
                    o[16 + l15] = cs1;
                }
            }
    }
}

// =====================================================================
// k_ce_pool v2: 256 thr; wave-parallel softmax over 32 via shfl_xor;
// w = softmax(sum_{h,it} accp / 512); pooled = sum_m w[m]*exv.
// accp: [16][1024][2][32]
// =====================================================================
__global__ __launch_bounds__(256) void k_ce_pool(const float* __restrict__ accp,
                                                 const float* __restrict__ exv,
                                                 float* __restrict__ pooled) {
    const int b = blockIdx.x;
    const int t = threadIdx.x;
    __shared__ float ww[32];
    if (t < 32) {
        float s = 0.f;
#pragma unroll
        for (int h = 0; h < 16; ++h) {
            s += accp[(((size_t)h * 1024 + b) * 2 + 0) * 32 + t];
            s += accp[(((size_t)h * 1024 + b) * 2 + 1) * 32 + t];
        }
        s *= (1.0f / 512.0f);
        float m = s;
        m = fmaxf(m, __shfl_xor(m, 1));
        m = fmaxf(m, __shfl_xor(m, 2));
        m = fmaxf(m, __shfl_xor(m, 4));
        m = fmaxf(m, __shfl_xor(m, 8));
        m = fmaxf(m, __shfl_xor(m, 16));
        float e = __expf(s - m);
        float sum = e;
        sum += __shfl_xor(sum, 1);
        sum += __shfl_xor(sum, 2);
        sum += __shfl_xor(sum, 4);
        sum += __shfl_xor(sum, 8);
        sum += __shfl_xor(sum, 16);
        ww[t] = e / sum;
    }
    __syncthreads();
    for (int d = t; d < 384; d += 256) {
        float v = 0.f;
#pragma unroll
        for (int m = 0; m < 32; ++m) v += ww[m] * exv[((size_t)b * 32 + m) * 384 + d];
        pooled[(size_t)b * 384 + d] = v;
    }
}

// =====================================================================
extern "C" void kernel_launch(void* const* d_in, const int* in_sizes, int n_in,
                              void* d_out, int out_size, void* d_ws, size_t ws_size,
                              hipStream_t stream) {
    const float* h_V    = (const float*)d_in[0];
    const float* h_EXV  = (const float*)d_in[1];
    const float* W_hV   = (const float*)d_in[2];
    const float* b_hV   = (const float*)d_in[3];
    const float* Wq_hv  = (const float*)d_in[4];
    const float* Wk_hv  = (const float*)d_in[5];
    const float* Wq_ce  = (const float*)d_in[6];
    const float* Wk_ce  = (const float*)d_in[7];
    const float* W_ce   = (const float*)d_in[8];
    const float* b_ce   = (const float*)d_in[9];
    const float* Wq_sce = (const float*)d_in[10];
    const float* Wk_sce = (const float*)d_in[11];
    float* out = (float*)d_out;

    char* ws = (char*)d_ws;
    f16*   mt_hv  = (f16*)(ws + 0);           //  2,097,152
    f16*   mt_sce = (f16*)(ws + 2097152);     //  2,097,152
    f16*   mt_ce  = (f16*)(ws + 4194304);     //  4,718,592
    float* hv     = (float*)(ws + 8912896);   //  1,048,576
    float* ce     = (float*)(ws + 9961472);   //  1,048,576
    float* accp   = (float*)(ws + 11010048);  //  4,194,304
    float* pooled = (float*)(ws + 15204352);  //  1,572,864  (total ~16.8 MB)
    float* wpart  = accp;                     // alias: lifetimes ordered

    k_mt3<<<dim3(16, 68), 256, 0, stream>>>(Wq_hv, Wk_hv, mt_hv,
                                            Wq_ce, Wk_ce, mt_ce,
                                            Wq_sce, Wk_sce, mt_sce);
    k_lin<<<256, 256, 0, stream>>>(h_V, W_hV, b_hV, hv, 128);
    k_small_int<<<dim3(32, 16), 256, 0, stream>>>(hv, mt_hv, wpart);
    k_small_fin<<<256, 256, 0, stream>>>(wpart, hv, out + 0, out + 65536);
    k_ce_int<<<dim3(512), 512, 49152, stream>>>(h_EXV, mt_ce, accp);
    k_ce_pool<<<1024, 256, 0, stream>>>(accp, h_EXV, pooled);
    k_lin<<<256, 256, 0, stream>>>(pooled, W_ce, b_ce, ce, 384);
    k_small_int<<<dim3(32, 16), 256, 0, stream>>>(ce, mt_sce, wpart);
    k_small_fin<<<256, 256, 0, stream>>>(wpart, ce, out + 66560, out + 132096);
}

// Round 17
// 286.810 us; speedup vs baseline: 1.0610x; 1.0610x over previous
//
#include <hip/hip_runtime.h>

typedef _Float16 f16;
typedef _Float16 f16x8 __attribute__((ext_vector_type(8)));
typedef _Float16 f16x4 __attribute__((ext_vector_type(4)));
typedef float f32x4 __attribute__((ext_vector_type(4)));

#define MFMA16(a, b, c) __builtin_amdgcn_mfma_f32_16x16x32_f16(a, b, c, 0, 0, 0)
#define MFMA16K16(a, b, c) __builtin_amdgcn_mfma_f32_16x16x16f16(a, b, c, 0, 0, 0)

// =====================================================================
// k_front: FUSED k_mt3 (blocks 0..1087) + k_lin(hv) (blocks 1088..1343).
// mt3: MT[h][e>>5][f][e&31] = sum_d Wq[h*H+d][e]*Wk[h*H+d][f].
// lin: hv[r][j] = h_V[r]@W_hV[j] + b. Dynamic LDS 39936.
// =====================================================================
__global__ __launch_bounds__(256) void k_front(const float* __restrict__ Wq_hv,
                                               const float* __restrict__ Wk_hv,
                                               f16* __restrict__ mt_hv,
                                               const float* __restrict__ Wq_ce,
                                               const float* __restrict__ Wk_ce,
                                               f16* __restrict__ mt_ce,
                                               const float* __restrict__ Wq_sce,
                                               const float* __restrict__ Wk_sce,
                                               f16* __restrict__ mt_sce,
                                               const float* __restrict__ h_V,
                                               const float* __restrict__ W_hV,
                                               const float* __restrict__ b_hV,
                                               float* __restrict__ hv) {
    extern __shared__ __align__(16) char smem[];
    const int bid = blockIdx.x;
    const int t = threadIdx.x;

    if (bid < 1088) {
        // ---------------- mt3 branch ----------------
        const int h = bid & 15;
        const int y = bid >> 4;
        const float *Wq, *Wk;
        f16* MT;
        int H, ty;
        if (y < 16)      { Wq = Wq_hv;  Wk = Wk_hv;  MT = mt_hv;  H = 256; ty = y; }
        else if (y < 52) { Wq = Wq_ce;  Wk = Wk_ce;  MT = mt_ce;  H = 384; ty = y - 16; }
        else             { Wq = Wq_sce; Wk = Wk_sce; MT = mt_sce; H = 256; ty = y - 52; }

        const int ntile = H >> 6;
        const int nkk = H >> 5;
        const int frow = (ty / ntile) * 64;
        const int ecol = (ty % ntile) * 64;
        const int lane = t & 63;
        const int w = t >> 6;
        const int wr = w >> 1, wc = w & 1;

        f16(*As)[40] = (f16(*)[40])smem;            // 5120 B
        f16(*Ks)[40] = (f16(*)[40])(smem + 5120);   // 5120 B

        f32x4 acc[2][2] = {};
        const int d = t >> 3;
        const int e8 = (t & 7) * 8;

        for (int kk = 0; kk < nkk; ++kk) {
            const float* gq = Wq + (size_t)(h * H + kk * 32 + d) * H + ecol + e8;
            const float* gk = Wk + (size_t)(h * H + kk * 32 + d) * H + frow + e8;
            float q[8], k[8];
#pragma unroll
            for (int i = 0; i < 8; ++i) { q[i] = gq[i]; k[i] = gk[i]; }
            __syncthreads();
#pragma unroll
            for (int i = 0; i < 8; ++i) { As[e8 + i][d] = (f16)q[i]; Ks[e8 + i][d] = (f16)k[i]; }
            __syncthreads();
            f16x8 a[2], b[2];
#pragma unroll
            for (int rt = 0; rt < 2; ++rt)
                a[rt] = *(const f16x8*)&Ks[wr * 32 + rt * 16 + (lane & 15)][(lane >> 4) * 8];
#pragma unroll
            for (int nt = 0; nt < 2; ++nt)
                b[nt] = *(const f16x8*)&As[wc * 32 + nt * 16 + (lane & 15)][(lane >> 4) * 8];
#pragma unroll
            for (int rt = 0; rt < 2; ++rt)
#pragma unroll
                for (int nt = 0; nt < 2; ++nt)
                    acc[rt][nt] = MFMA16(a[rt], b[nt], acc[rt][nt]);
        }
#pragma unroll
        for (int rt = 0; rt < 2; ++rt)
#pragma unroll
            for (int nt = 0; nt < 2; ++nt)
#pragma unroll
                for (int j = 0; j < 4; ++j) {
                    int f = frow + wr * 32 + rt * 16 + (lane >> 4) * 4 + j;
                    int e = ecol + wc * 32 + nt * 16 + (lane & 15);
                    MT[(((size_t)h * nkk + (e >> 5)) * H + f) * 32 + (e & 31)] = (f16)acc[rt][nt][j];
                }
    } else {
        // ---------------- lin(hv) branch ----------------
        const int r0 = (bid - 1088) * 4;
        const int K = 128;
        float(*ins)[384] = (float(*)[384])smem;               // 6144 B
        float(*Ws)[33] = (float(*)[33])(smem + 6144);         // 33792 B
#pragma unroll
        for (int r = 0; r < 4; ++r)
            for (int off = t; off < K; off += 256)
                ins[r][off] = h_V[(size_t)(r0 + r) * K + off];
        float acc[4] = {};
        for (int d0 = 0; d0 < K; d0 += 32) {
            __syncthreads();
            for (int i = t; i < 256 * 32; i += 256) {
                int j = i >> 5, dd = i & 31;
                Ws[j][dd] = W_hV[(size_t)j * K + d0 + dd];
            }
            __syncthreads();
#pragma unroll 8
            for (int dd = 0; dd < 32; ++dd) {
                float wv = Ws[t][dd];
#pragma unroll
                for (int r = 0; r < 4; ++r) acc[r] += wv * ins[r][d0 + dd];
            }
        }
        float bv = b_hV[t];
#pragma unroll
        for (int r = 0; r < 4; ++r) hv[(size_t)(r0 + r) * 256 + t] = acc[r] + bv;
    }
}

// =====================================================================
// k_lin: standalone (ce path). Static LDS.
// =====================================================================
__global__ __launch_bounds__(256) void k_lin(const float* __restrict__ in,
                                             const float* __restrict__ W,
                                             const float* __restrict__ bias,
                                             float* __restrict__ out, int K) {
    const int t = threadIdx.x;
    const int r0 = blockIdx.x * 4;
    __shared__ float ins[4][384];
    __shared__ float Ws[256][33];
#pragma unroll
    for (int r = 0; r < 4; ++r)
        for (int off = t; off < K; off += 256)
            ins[r][off] = in[(size_t)(r0 + r) * K + off];
    float acc[4] = {};
    for (int d0 = 0; d0 < K; d0 += 32) {
        __syncthreads();
        for (int i = t; i < 256 * 32; i += 256) {
            int j = i >> 5, dd = i & 31;
            Ws[j][dd] = W[(size_t)j * K + d0 + dd];
        }
        __syncthreads();
#pragma unroll 8
        for (int dd = 0; dd < 32; ++dd) {
            float wv = Ws[t][dd];
#pragma unroll
            for (int r = 0; r < 4; ++r) acc[r] += wv * ins[r][d0 + dd];
        }
    }
    float bv = bias[t];
#pragma unroll
    for (int r = 0; r < 4; ++r) out[(size_t)(r0 + r) * 256 + t] = acc[r] + bv;
}

// =====================================================================
// k_small_int: standalone (sce path), 8 pos-groups/block, grid (32,16).
// =====================================================================
__global__ __launch_bounds__(256) void k_small_int(const float* __restrict__ X,
                                                   const f16* __restrict__ MT,
                                                   float* __restrict__ wpart) {
    const int t = threadIdx.x;
    const int lane = t & 63;
    const int w = t >> 6;
    const int g = lane >> 4;
    const int l15 = lane & 15;
    const int pos0 = blockIdx.x * 8;
    const int h = blockIdx.y;

    __shared__ __align__(16) f16 Xs[32][264];
    __shared__ __align__(16) f16 Ts[32][264];

    {
        int row = t >> 3, d0 = (t & 7) * 32;
        int s = row & 3, p = row >> 2;
        const float* gx = X + (size_t)(s * 256 + pos0 + p) * 256 + d0;
#pragma unroll
        for (int i = 0; i < 32; i += 8) {
            float4 v0 = *(const float4*)(gx + i);
            float4 v1 = *(const float4*)(gx + i + 4);
            f16x8 o;
            o[0] = (f16)v0.x; o[1] = (f16)v0.y; o[2] = (f16)v0.z; o[3] = (f16)v0.w;
            o[4] = (f16)v1.x; o[5] = (f16)v1.y; o[6] = (f16)v1.z; o[7] = (f16)v1.w;
            *(f16x8*)&Xs[row][d0 + i] = o;
        }
    }
    __syncthreads();

    const f16* mh = MT + (size_t)h * 8 * 256 * 32;
    const int fb = w * 64 + l15;
    f32x4 acc[2][4] = {};
    f16x8 bq[4], bn[4];
#pragma unroll
    for (int nt = 0; nt < 4; ++nt)
        bq[nt] = *(const f16x8*)(mh + (size_t)(fb + nt * 16) * 32 + g * 8);
#pragma unroll
    for (int kk = 0; kk < 8; ++kk) {
        if (kk < 7) {
#pragma unroll
            for (int nt = 0; nt < 4; ++nt)
                bn[nt] = *(const f16x8*)(mh + ((size_t)(kk + 1) * 256 + fb + nt * 16) * 32 + g * 8);
        }
        f16x8 a[2];
#pragma unroll
        for (int mt = 0; mt < 2; ++mt)
            a[mt] = *(const f16x8*)&Xs[mt * 16 + l15][kk * 32 + g * 8];
#pragma unroll
        for (int mt = 0; mt < 2; ++mt)
#pragma unroll
            for (int nt = 0; nt < 4; ++nt)
                acc[mt][nt] = MFMA16(a[mt], bq[nt], acc[mt][nt]);
#pragma unroll
        for (int nt = 0; nt < 4; ++nt) bq[nt] = bn[nt];
    }
#pragma unroll
    for (int mt = 0; mt < 2; ++mt)
#pragma unroll
        for (int nt = 0; nt < 4; ++nt)
#pragma unroll
            for (int j = 0; j < 4; ++j)
                Ts[mt * 16 + g * 4 + j][w * 64 + nt * 16 + l15] = (f16)acc[mt][nt][j];
    __syncthreads();

    if (w < 2) {
        f32x4 sacc = {};
#pragma unroll
        for (int ks = 0; ks < 8; ++ks) {
            f16x8 a = *(const f16x8*)&Ts[w * 16 + l15][ks * 32 + g * 8];
            f16x8 b = *(const f16x8*)&Xs[w * 16 + l15][ks * 32 + g * 8];
            sacc = MFMA16(a, b, sacc);
        }
        if ((l15 >> 2) == g) {
            const float scale = 1.0f / 16.0f; // 1/sqrt(256)
            float add = 0.f;
#pragma unroll
            for (int j = 0; j < 4; ++j) {
                float v = sacc[j] * scale;
                float m = v;
                m = fmaxf(m, __shfl_xor(m, 1));
                m = fmaxf(m, __shfl_xor(m, 2));
                float e = expf(v - m);
                float s2 = e;
                s2 += __shfl_xor(s2, 1);
                s2 += __shfl_xor(s2, 2);
                add += e / s2;
            }
            int pg = pos0 + w * 4 + g;
            wpart[((size_t)h * 256 + pg) * 4 + (l15 & 3)] = add;
        }
    }
}

// =====================================================================
// k_small_fin: standalone (sce path).
// =====================================================================
__global__ __launch_bounds__(256) void k_small_fin(const float* __restrict__ wpart,
                                                   const float* __restrict__ X,
                                                   float* __restrict__ out_int,
                                                   float* __restrict__ out_w) {
    const int pos = blockIdx.x, t = threadIdx.x;
    __shared__ float red[64];
    __shared__ float ws[4];
    if (t < 64) red[t] = wpart[((size_t)(t >> 2) * 256 + pos) * 4 + (t & 3)];
    __syncthreads();
    if (t == 0) {
        float v[4];
#pragma unroll
        for (int s = 0; s < 4; ++s) {
            float x = 0.f;
            for (int hh = 0; hh < 16; ++hh) x += red[hh * 4 + s];
            v[s] = x * (1.0f / 64.0f);
        }
        float m = fmaxf(fmaxf(v[0], v[1]), fmaxf(v[2], v[3]));
        float sum = 0.f;
#pragma unroll
        for (int s = 0; s < 4; ++s) { v[s] = expf(v[s] - m); sum += v[s]; }
#pragma unroll
        for (int s = 0; s < 4; ++s) ws[s] = v[s] / sum;
    }
    __syncthreads();
    if (t < 4) out_w[pos * 4 + t] = ws[t];
    float v = 0.f;
#pragma unroll
    for (int s = 0; s < 4; ++s) v += ws[s] * X[(size_t)(s * 256 + pos) * 256 + t];
    out_int[(size_t)pos * 256 + t] = v;
}

// =====================================================================
// k_mid: FUSED ce_int v15 (blocks 0..511) + small_int hv (blocks 512..1023).
// ce_int: barrier-free per-wave-head (proven ~186 us). small_int: 256-thr
// semantics inside 512-thr block, barrier-safe guards. Dyn LDS 49152.
// =====================================================================
__global__ __launch_bounds__(512) void k_mid(const float* __restrict__ Xg32,
                                             const f16* __restrict__ MTce,
                                             float* __restrict__ acc_out,
                                             const float* __restrict__ hv,
                                             const f16* __restrict__ MThv,
                                             float* __restrict__ wpart) {
    extern __shared__ __align__(16) char smem[];
    const int t = threadIdx.x;
    const int lane = t & 63;
    const int w = t >> 6;
    const int g = lane >> 4;
    const int l15 = lane & 15;

    if (blockIdx.x < 512) {
        // ---------------- ce_int branch (v15, byte-identical) ----------------
        const int bg = blockIdx.x;
        {
            const float* xg = Xg32 + (size_t)bg * 64 * 384;
#pragma unroll
            for (int p = 0; p < 6; ++p) {
                int idx = p * 512 + t;
                int row = idx / 48, s = idx - row * 48;
                int c = s ^ (row & 7);
                const float* src = xg + row * 384 + c * 8;
                float4 v0 = *(const float4*)src;
                float4 v1 = *(const float4*)(src + 4);
                f16x8 o;
                o[0] = (f16)v0.x; o[1] = (f16)v0.y; o[2] = (f16)v0.z; o[3] = (f16)v0.w;
                o[4] = (f16)v1.x; o[5] = (f16)v1.y; o[6] = (f16)v1.z; o[7] = (f16)v1.w;
                *(f16x8*)(smem + idx * 16) = o;
            }
        }
        __syncthreads();

        const float scale = 0.051031036307982884f; // 1/sqrt(384)

        for (int h2 = 0; h2 < 2; ++h2) {
            const int h = h2 * 8 + w;
            const f16* mh = MTce + (size_t)h * 12 * 12288;

            f32x4 S2[2][2][2] = {};
            f16x8 A[2][2];
#pragma unroll
            for (int ft = 0; ft < 2; ++ft)
                A[0][ft] = *(const f16x8*)(mh + (size_t)(ft * 16 + l15) * 32 + g * 8);

            for (int c = 0; c < 12; ++c) {
                f32x4 acc[2][4] = {};
#pragma unroll
                for (int kk = 0; kk < 12; ++kk) {
                    const int step = c * 12 + kk;
                    {
                        int ns = step + 1;
                        int nc = ns / 12, nk = ns - nc * 12;
                        if (nc > 11) { nc = 11; nk = 11; }
#pragma unroll
                        for (int ft = 0; ft < 2; ++ft)
                            A[(step + 1) & 1][ft] =
                                *(const f16x8*)(mh + (size_t)nk * 12288 +
                                                (size_t)(nc * 32 + ft * 16 + l15) * 32 + g * 8);
                    }
                    f16x8 xb[4];
#pragma unroll
                    for (int mt = 0; mt < 4; ++mt) {
                        int row = mt * 16 + l15;
                        int ch = kk * 4 + g;
                        xb[mt] = *(const f16x8*)(smem + row * 768 + ((ch ^ (row & 7)) << 4));
                    }
                    __builtin_amdgcn_s_setprio(1);
#pragma unroll
                    for (int ft = 0; ft < 2; ++ft)
#pragma unroll
                        for (int mt = 0; mt < 4; ++mt)
                            acc[ft][mt] = MFMA16(A[step & 1][ft], xb[mt], acc[ft][mt]);
                    __builtin_amdgcn_s_setprio(0);
                }

                f16x4 bf[2][4];
#pragma unroll
                for (int ft = 0; ft < 2; ++ft)
#pragma unroll
                    for (int mt = 0; mt < 4; ++mt) {
                        f32x4 v = acc[ft][mt];
                        f16x4 o;
                        o[0] = (f16)v[0]; o[1] = (f16)v[1]; o[2] = (f16)v[2]; o[3] = (f16)v[3];
                        bf[ft][mt] = o;
                    }

#pragma unroll
                for (int b = 0; b < 2; ++b)
#pragma unroll
                    for (int ks = 0; ks < 2; ++ks)
#pragma unroll
                        for (int it = 0; it < 2; ++it) {
                            int row = b * 32 + it * 16 + l15;
                            int ch = c * 4 + ks * 2 + (g >> 1);
                            f16x4 av = *(const f16x4*)(smem + row * 768 +
                                                       ((ch ^ (row & 7)) << 4) + 8 * (g & 1));
#pragma unroll
                            for (int lt = 0; lt < 2; ++lt)
                                S2[b][it][lt] = MFMA16K16(av, bf[ks][2 * b + lt], S2[b][it][lt]);
                        }
            }

#pragma unroll
            for (int b = 0; b < 2; ++b)
#pragma unroll
                for (int it = 0; it < 2; ++it) {
                    f32x4 sum0 = S2[b][it][0];
                    f32x4 sum1 = S2[b][it][1];
                    float cs0 = 0.f, cs1 = 0.f;
#pragma unroll
                    for (int j = 0; j < 4; ++j) {
                        float v0 = sum0[j] * scale, v1 = sum1[j] * scale;
                        float m = fmaxf(v0, v1);
                        m = fmaxf(m, __shfl_xor(m, 1));
                        m = fmaxf(m, __shfl_xor(m, 2));
                        m = fmaxf(m, __shfl_xor(m, 4));
                        m = fmaxf(m, __shfl_xor(m, 8));
                        float e0 = __expf(v0 - m), e1 = __expf(v1 - m);
                        float s = e0 + e1;
                        s += __shfl_xor(s, 1);
                        s += __shfl_xor(s, 2);
                        s += __shfl_xor(s, 4);
                        s += __shfl_xor(s, 8);
                        float inv = 1.f / s;
                        cs0 += e0 * inv;
                        cs1 += e1 * inv;
                    }
                    cs0 += __shfl_xor(cs0, 16); cs0 += __shfl_xor(cs0, 32);
                    cs1 += __shfl_xor(cs1, 16); cs1 += __shfl_xor(cs1, 32);
                    if (lane < 16) {
                        float* o = acc_out + (((size_t)h * 1024 + bg * 2 + b) * 2 + it) * 32;
                        o[l15] = cs0;
                        o[16 + l15] = cs1;
                    }
                }
        }
    } else {
        // ---------------- small_int(hv) branch (256-thr semantics) ----------------
        const int bid2 = blockIdx.x - 512;
        const int pos0 = (bid2 & 31) * 8;
        const int h = bid2 >> 5;

        f16(*Xs)[264] = (f16(*)[264])smem;                 // 16896 B
        f16(*Ts)[264] = (f16(*)[264])(smem + 16896);       // 16896 B

        if (t < 256) {
            int row = t >> 3, d0 = (t & 7) * 32;
            int s = row & 3, p = row >> 2;
            const float* gx = hv + (size_t)(s * 256 + pos0 + p) * 256 + d0;
#pragma unroll
            for (int i = 0; i < 32; i += 8) {
                float4 v0 = *(const float4*)(gx + i);
                float4 v1 = *(const float4*)(gx + i + 4);
                f16x8 o;
                o[0] = (f16)v0.x; o[1] = (f16)v0.y; o[2] = (f16)v0.z; o[3] = (f16)v0.w;
                o[4] = (f16)v1.x; o[5] = (f16)v1.y; o[6] = (f16)v1.z; o[7] = (f16)v1.w;
                *(f16x8*)&Xs[row][d0 + i] = o;
            }
        }
        __syncthreads();

        if (t < 256) {
            const f16* mh = MThv + (size_t)h * 8 * 256 * 32;
            const int fb = w * 64 + l15;
            f32x4 acc[2][4] = {};
            f16x8 bq[4], bn[4];
#pragma unroll
            for (int nt = 0; nt < 4; ++nt)
                bq[nt] = *(const f16x8*)(mh + (size_t)(fb + nt * 16) * 32 + g * 8);
#pragma unroll
            for (int kk = 0; kk < 8; ++kk) {
                if (kk < 7) {
#pragma unroll
                    for (int nt = 0; nt < 4; ++nt)
                        bn[nt] = *(const f16x8*)(mh + ((size_t)(kk + 1) * 256 + fb + nt * 16) * 32 + g * 8);
                }
                f16x8 a[2];
#pragma unroll
                for (int mt = 0; mt < 2; ++mt)
                    a[mt] = *(const f16x8*)&Xs[mt * 16 + l15][kk * 32 + g * 8];
#pragma unroll
                for (int mt = 0; mt < 2; ++mt)
#pragma unroll
                    for (int nt = 0; nt < 4; ++nt)
                        acc[mt][nt] = MFMA16(a[mt], bq[nt], acc[mt][nt]);
#pragma unroll
                for (int nt = 0; nt < 4; ++nt) bq[nt] = bn[nt];
            }
#pragma unroll
            for (int mt = 0; mt < 2; ++mt)
#pragma unroll
                for (int nt = 0; nt < 4; ++nt)
#pragma unroll
                    for (int j = 0; j < 4; ++j)
                        Ts[mt * 16 + g * 4 + j][w * 64 + nt * 16 + l15] = (f16)acc[mt][nt][j];
        }
        __syncthreads();

        if (t < 128) {
            f32x4 sacc = {};
#pragma unroll
            for (int ks = 0; ks < 8; ++ks) {
                f16x8 a = *(const f16x8*)&Ts[w * 16 + l15][ks * 32 + g * 8];
                f16x8 b = *(const f16x8*)&Xs[w * 16 + l15][ks * 32 + g * 8];
                sacc = MFMA16(a, b, sacc);
            }
            if ((l15 >> 2) == g) {
                const float scale = 1.0f / 16.0f; // 1/sqrt(256)
                float add = 0.f;
#pragma unroll
                for (int j = 0; j < 4; ++j) {
                    float v = sacc[j] * scale;
                    float m = v;
                    m = fmaxf(m, __shfl_xor(m, 1));
                    m = fmaxf(m, __shfl_xor(m, 2));
                    float e = expf(v - m);
                    float s2 = e;
                    s2 += __shfl_xor(s2, 1);
                    s2 += __shfl_xor(s2, 2);
                    add += e / s2;
                }
                int pg = pos0 + w * 4 + g;
                wpart[((size_t)h * 256 + pg) * 4 + (l15 & 3)] = add;
            }
        }
    }
}

// =====================================================================
// k_back: FUSED ce_pool (blocks 0..1023) + small_fin hv (1024..1279).
// =====================================================================
__global__ __launch_bounds__(256) void k_back(const float* __restrict__ accp,
                                              const float* __restrict__ exv,
                                              float* __restrict__ pooled,
                                              const float* __restrict__ wpart,
                                              const float* __restrict__ hv,
                                              float* __restrict__ out_int,
                                              float* __restrict__ out_w) {
    const int t = threadIdx.x;
    __shared__ float ww[32];
    __shared__ float red[64];
    __shared__ float ws[4];

    if (blockIdx.x < 1024) {
        const int b = blockIdx.x;
        if (t < 32) {
            float s = 0.f;
#pragma unroll
            for (int h = 0; h < 16; ++h) {
                s += accp[(((size_t)h * 1024 + b) * 2 + 0) * 32 + t];
                s += accp[(((size_t)h * 1024 + b) * 2 + 1) * 32 + t];
            }
            s *= (1.0f / 512.0f);
            float m = s;
            m = fmaxf(m, __shfl_xor(m, 1));
            m = fmaxf(m, __shfl_xor(m, 2));
            m = fmaxf(m, __shfl_xor(m, 4));
            m = fmaxf(m, __shfl_xor(m, 8));
            m = fmaxf(m, __shfl_xor(m, 16));
            float e = __expf(s - m);
            float sum = e;
            sum += __shfl_xor(sum, 1);
            sum += __shfl_xor(sum, 2);
            sum += __shfl_xor(sum, 4);
            sum += __shfl_xor(sum, 8);
            sum += __shfl_xor(sum, 16);
            ww[t] = e / sum;
        }
        __syncthreads();
        for (int d = t; d < 384; d += 256) {
            float v = 0.f;
#pragma unroll
            for (int m = 0; m < 32; ++m) v += ww[m] * exv[((size_t)b * 32 + m) * 384 + d];
            pooled[(size_t)b * 384 + d] = v;
        }
    } else {
        const int pos = blockIdx.x - 1024;
        if (t < 64) red[t] = wpart[((size_t)(t >> 2) * 256 + pos) * 4 + (t & 3)];
        __syncthreads();
        if (t == 0) {
            float v[4];
#pragma unroll
            for (int s = 0; s < 4; ++s) {
                float x = 0.f;
                for (int hh = 0; hh < 16; ++hh) x += red[hh * 4 + s];
                v[s] = x * (1.0f / 64.0f);
            }
            float m = fmaxf(fmaxf(v[0], v[1]), fmaxf(v[2], v[3]));
            float sum = 0.f;
#pragma unroll
            for (int s = 0; s < 4; ++s) { v[s] = expf(v[s] - m); sum += v[s]; }
#pragma unroll
            for (int s = 0; s < 4; ++s) ws[s] = v[s] / sum;
        }
        __syncthreads();
        if (t < 4) out_w[pos * 4 + t] = ws[t];
        float v = 0.f;
#pragma unroll
        for (int s = 0; s < 4; ++s) v += ws[s] * hv[(size_t)(s * 256 + pos) * 256 + t];
        out_int[(size_t)pos * 256 + t] = v;
    }
}

// =====================================================================
extern "C" void kernel_launch(void* const* d_in, const int* in_sizes, int n_in,
                              void* d_out, int out_size, void* d_ws, size_t ws_size,
                              hipStream_t stream) {
    const float* h_V    = (const float*)d_in[0];
    const float* h_EXV  = (const float*)d_in[1];
    const float* W_hV   = (const float*)d_in[2];
    const float* b_hV   = (const float*)d_in[3];
    const float* Wq_hv  = (const float*)d_in[4];
    const float* Wk_hv  = (const float*)d_in[5];
    const float* Wq_ce  = (const float*)d_in[6];
    const float* Wk_ce  = (const float*)d_in[7];
    const float* W_ce   = (const float*)d_in[8];
    const float* b_ce   = (const float*)d_in[9];
    const float* Wq_sce = (const float*)d_in[10];
    const float* Wk_sce = (const float*)d_in[11];
    float* out = (float*)d_out;

    char* ws = (char*)d_ws;
    f16*   mt_hv  = (f16*)(ws + 0);           //  2,097,152
    f16*   mt_sce = (f16*)(ws + 2097152);     //  2,097,152
    f16*   mt_ce  = (f16*)(ws + 4194304);     //  4,718,592
    float* hv     = (float*)(ws + 8912896);   //  1,048,576
    float* ce     = (float*)(ws + 9961472);   //  1,048,576
    float* accp   = (float*)(ws + 11010048);  //  4,194,304
    float* pooled = (float*)(ws + 15204352);  //  1,572,864
    float* wpart  = (float*)(ws + 16777216);  //     65,536  (own buffer: concurrent with accp)

    k_front<<<1344, 256, 39936, stream>>>(Wq_hv, Wk_hv, mt_hv,
                                          Wq_ce, Wk_ce, mt_ce,
                                          Wq_sce, Wk_sce, mt_sce,
                                          h_V, W_hV, b_hV, hv);
    k_mid<<<1024, 512, 49152, stream>>>(h_EXV, mt_ce, accp, hv, mt_hv, wpart);
    k_back<<<1280, 256, 0, stream>>>(accp, h_EXV, pooled, wpart, hv,
                                     out + 0, out + 65536);
    k_lin<<<256, 256, 0, stream>>>(pooled, W_ce, b_ce, ce, 384);
    k_small_int<<<dim3(32, 16), 256, 0, stream>>>(ce, mt_sce, wpart);
    k_small_fin<<<256, 256, 0, stream>>>(wpart, ce, out + 66560, out + 132096);
}

// Round 18
// 280.395 us; speedup vs baseline: 1.0852x; 1.0229x over previous
//
#include <hip/hip_runtime.h>

typedef _Float16 f16;
typedef _Float16 f16x8 __attribute__((ext_vector_type(8)));
typedef _Float16 f16x4 __attribute__((ext_vector_type(4)));
typedef float f32x4 __attribute__((ext_vector_type(4)));

#define MFMA16(a, b, c) __builtin_amdgcn_mfma_f32_16x16x32_f16(a, b, c, 0, 0, 0)
#define MFMA16K16(a, b, c) __builtin_amdgcn_mfma_f32_16x16x16f16(a, b, c, 0, 0, 0)

// =====================================================================
// k_front: FUSED k_mt3 (blocks 0..1087, double-buffered: 1 barrier/kk)
// + k_lin(hv) (blocks 1088..1343). Dynamic LDS 39936.
// =====================================================================
__global__ __launch_bounds__(256) void k_front(const float* __restrict__ Wq_hv,
                                               const float* __restrict__ Wk_hv,
                                               f16* __restrict__ mt_hv,
                                               const float* __restrict__ Wq_ce,
                                               const float* __restrict__ Wk_ce,
                                               f16* __restrict__ mt_ce,
                                               const float* __restrict__ Wq_sce,
                                               const float* __restrict__ Wk_sce,
                                               f16* __restrict__ mt_sce,
                                               const float* __restrict__ h_V,
                                               const float* __restrict__ W_hV,
                                               const float* __restrict__ b_hV,
                                               float* __restrict__ hv) {
    extern __shared__ __align__(16) char smem[];
    const int bid = blockIdx.x;
    const int t = threadIdx.x;

    if (bid < 1088) {
        // ---------------- mt3 branch (double-buffered) ----------------
        const int h = bid & 15;
        const int y = bid >> 4;
        const float *Wq, *Wk;
        f16* MT;
        int H, ty;
        if (y < 16)      { Wq = Wq_hv;  Wk = Wk_hv;  MT = mt_hv;  H = 256; ty = y; }
        else if (y < 52) { Wq = Wq_ce;  Wk = Wk_ce;  MT = mt_ce;  H = 384; ty = y - 16; }
        else             { Wq = Wq_sce; Wk = Wk_sce; MT = mt_sce; H = 256; ty = y - 52; }

        const int ntile = H >> 6;
        const int nkk = H >> 5;
        const int frow = (ty / ntile) * 64;
        const int ecol = (ty % ntile) * 64;
        const int lane = t & 63;
        const int w = t >> 6;
        const int wr = w >> 1, wc = w & 1;

        // buffers: As[2][64][40], Ks[2][64][40] = 20480 B
        f16(*As)[64][40] = (f16(*)[64][40])smem;
        f16(*Ks)[64][40] = (f16(*)[64][40])(smem + 10240);

        f32x4 acc[2][2] = {};
        const int d = t >> 3;
        const int e8 = (t & 7) * 8;

        // prologue: stage kk=0 into buf 0
        {
            const float* gq = Wq + (size_t)(h * H + d) * H + ecol + e8;
            const float* gk = Wk + (size_t)(h * H + d) * H + frow + e8;
#pragma unroll
            for (int i = 0; i < 8; ++i) {
                As[0][e8 + i][d] = (f16)gq[i];
                Ks[0][e8 + i][d] = (f16)gk[i];
            }
        }
        __syncthreads();

        for (int kk = 0; kk < nkk; ++kk) {
            float q[8], k[8];
            if (kk + 1 < nkk) {
                const float* gq = Wq + (size_t)(h * H + (kk + 1) * 32 + d) * H + ecol + e8;
                const float* gk = Wk + (size_t)(h * H + (kk + 1) * 32 + d) * H + frow + e8;
#pragma unroll
                for (int i = 0; i < 8; ++i) { q[i] = gq[i]; k[i] = gk[i]; }
            }
            const int cur = kk & 1;
            f16x8 a[2], b[2];
#pragma unroll
            for (int rt = 0; rt < 2; ++rt)
                a[rt] = *(const f16x8*)&Ks[cur][wr * 32 + rt * 16 + (lane & 15)][(lane >> 4) * 8];
#pragma unroll
            for (int nt = 0; nt < 2; ++nt)
                b[nt] = *(const f16x8*)&As[cur][wc * 32 + nt * 16 + (lane & 15)][(lane >> 4) * 8];
#pragma unroll
            for (int rt = 0; rt < 2; ++rt)
#pragma unroll
                for (int nt = 0; nt < 2; ++nt)
                    acc[rt][nt] = MFMA16(a[rt], b[nt], acc[rt][nt]);
            if (kk + 1 < nkk) {
                const int nxt = (kk + 1) & 1;
#pragma unroll
                for (int i = 0; i < 8; ++i) {
                    As[nxt][e8 + i][d] = (f16)q[i];
                    Ks[nxt][e8 + i][d] = (f16)k[i];
                }
                __syncthreads();
            }
        }
#pragma unroll
        for (int rt = 0; rt < 2; ++rt)
#pragma unroll
            for (int nt = 0; nt < 2; ++nt)
#pragma unroll
                for (int j = 0; j < 4; ++j) {
                    int f = frow + wr * 32 + rt * 16 + (lane >> 4) * 4 + j;
                    int e = ecol + wc * 32 + nt * 16 + (lane & 15);
                    MT[(((size_t)h * nkk + (e >> 5)) * H + f) * 32 + (e & 31)] = (f16)acc[rt][nt][j];
                }
    } else {
        // ---------------- lin(hv) branch ----------------
        const int r0 = (bid - 1088) * 4;
        const int K = 128;
        float(*ins)[384] = (float(*)[384])smem;               // 6144 B
        float(*Ws)[33] = (float(*)[33])(smem + 6144);         // 33792 B
#pragma unroll
        for (int r = 0; r < 4; ++r)
            for (int off = t; off < K; off += 256)
                ins[r][off] = h_V[(size_t)(r0 + r) * K + off];
        float acc[4] = {};
        for (int d0 = 0; d0 < K; d0 += 32) {
            __syncthreads();
            for (int i = t; i < 256 * 32; i += 256) {
                int j = i >> 5, dd = i & 31;
                Ws[j][dd] = W_hV[(size_t)j * K + d0 + dd];
            }
            __syncthreads();
#pragma unroll 8
            for (int dd = 0; dd < 32; ++dd) {
                float wv = Ws[t][dd];
#pragma unroll
                for (int r = 0; r < 4; ++r) acc[r] += wv * ins[r][d0 + dd];
            }
        }
        float bv = b_hV[t];
#pragma unroll
        for (int r = 0; r < 4; ++r) hv[(size_t)(r0 + r) * 256 + t] = acc[r] + bv;
    }
}

// =====================================================================
// k_lin: standalone (ce path). Static LDS.
// =====================================================================
__global__ __launch_bounds__(256) void k_lin(const float* __restrict__ in,
                                             const float* __restrict__ W,
                                             const float* __restrict__ bias,
                                             float* __restrict__ out, int K) {
    const int t = threadIdx.x;
    const int r0 = blockIdx.x * 4;
    __shared__ float ins[4][384];
    __shared__ float Ws[256][33];
#pragma unroll
    for (int r = 0; r < 4; ++r)
        for (int off = t; off < K; off += 256)
            ins[r][off] = in[(size_t)(r0 + r) * K + off];
    float acc[4] = {};
    for (int d0 = 0; d0 < K; d0 += 32) {
        __syncthreads();
        for (int i = t; i < 256 * 32; i += 256) {
            int j = i >> 5, dd = i & 31;
            Ws[j][dd] = W[(size_t)j * K + d0 + dd];
        }
        __syncthreads();
#pragma unroll 8
        for (int dd = 0; dd < 32; ++dd) {
            float wv = Ws[t][dd];
#pragma unroll
            for (int r = 0; r < 4; ++r) acc[r] += wv * ins[r][d0 + dd];
        }
    }
    float bv = bias[t];
#pragma unroll
    for (int r = 0; r < 4; ++r) out[(size_t)(r0 + r) * 256 + t] = acc[r] + bv;
}

// =====================================================================
// k_small_int: standalone (sce path), 8 pos-groups/block, grid (32,16).
// =====================================================================
__global__ __launch_bounds__(256) void k_small_int(const float* __restrict__ X,
                                                   const f16* __restrict__ MT,
                                                   float* __restrict__ wpart) {
    const int t = threadIdx.x;
    const int lane = t & 63;
    const int w = t >> 6;
    const int g = lane >> 4;
    const int l15 = lane & 15;
    const int pos0 = blockIdx.x * 8;
    const int h = blockIdx.y;

    __shared__ __align__(16) f16 Xs[32][264];
    __shared__ __align__(16) f16 Ts[32][264];

    {
        int row = t >> 3, d0 = (t & 7) * 32;
        int s = row & 3, p = row >> 2;
        const float* gx = X + (size_t)(s * 256 + pos0 + p) * 256 + d0;
#pragma unroll
        for (int i = 0; i < 32; i += 8) {
            float4 v0 = *(const float4*)(gx + i);
            float4 v1 = *(const float4*)(gx + i + 4);
            f16x8 o;
            o[0] = (f16)v0.x; o[1] = (f16)v0.y; o[2] = (f16)v0.z; o[3] = (f16)v0.w;
            o[4] = (f16)v1.x; o[5] = (f16)v1.y; o[6] = (f16)v1.z; o[7] = (f16)v1.w;
            *(f16x8*)&Xs[row][d0 + i] = o;
        }
    }
    __syncthreads();

    const f16* mh = MT + (size_t)h * 8 * 256 * 32;
    const int fb = w * 64 + l15;
    f32x4 acc[2][4] = {};
    f16x8 bq[4], bn[4];
#pragma unroll
    for (int nt = 0; nt < 4; ++nt)
        bq[nt] = *(const f16x8*)(mh + (size_t)(fb + nt * 16) * 32 + g * 8);
#pragma unroll
    for (int kk = 0; kk < 8; ++kk) {
        if (kk < 7) {
#pragma unroll
            for (int nt = 0; nt < 4; ++nt)
                bn[nt] = *(const f16x8*)(mh + ((size_t)(kk + 1) * 256 + fb + nt * 16) * 32 + g * 8);
        }
        f16x8 a[2];
#pragma unroll
        for (int mt = 0; mt < 2; ++mt)
            a[mt] = *(const f16x8*)&Xs[mt * 16 + l15][kk * 32 + g * 8];
#pragma unroll
        for (int mt = 0; mt < 2; ++mt)
#pragma unroll
            for (int nt = 0; nt < 4; ++nt)
                acc[mt][nt] = MFMA16(a[mt], bq[nt], acc[mt][nt]);
#pragma unroll
        for (int nt = 0; nt < 4; ++nt) bq[nt] = bn[nt];
    }
#pragma unroll
    for (int mt = 0; mt < 2; ++mt)
#pragma unroll
        for (int nt = 0; nt < 4; ++nt)
#pragma unroll
            for (int j = 0; j < 4; ++j)
                Ts[mt * 16 + g * 4 + j][w * 64 + nt * 16 + l15] = (f16)acc[mt][nt][j];
    __syncthreads();

    if (w < 2) {
        f32x4 sacc = {};
#pragma unroll
        for (int ks = 0; ks < 8; ++ks) {
            f16x8 a = *(const f16x8*)&Ts[w * 16 + l15][ks * 32 + g * 8];
            f16x8 b = *(const f16x8*)&Xs[w * 16 + l15][ks * 32 + g * 8];
            sacc = MFMA16(a, b, sacc);
        }
        if ((l15 >> 2) == g) {
            const float scale = 1.0f / 16.0f; // 1/sqrt(256)
            float add = 0.f;
#pragma unroll
            for (int j = 0; j < 4; ++j) {
                float v = sacc[j] * scale;
                float m = v;
                m = fmaxf(m, __shfl_xor(m, 1));
                m = fmaxf(m, __shfl_xor(m, 2));
                float e = __expf(v - m);
                float s2 = e;
                s2 += __shfl_xor(s2, 1);
                s2 += __shfl_xor(s2, 2);
                add += e / s2;
            }
            int pg = pos0 + w * 4 + g;
            wpart[((size_t)h * 256 + pg) * 4 + (l15 & 3)] = add;
        }
    }
}

// =====================================================================
// k_small_fin: standalone (sce path).
// =====================================================================
__global__ __launch_bounds__(256) void k_small_fin(const float* __restrict__ wpart,
                                                   const float* __restrict__ X,
                                                   float* __restrict__ out_int,
                                                   float* __restrict__ out_w) {
    const int pos = blockIdx.x, t = threadIdx.x;
    __shared__ float red[64];
    __shared__ float ws[4];
    if (t < 64) red[t] = wpart[((size_t)(t >> 2) * 256 + pos) * 4 + (t & 3)];
    __syncthreads();
    if (t == 0) {
        float v[4];
#pragma unroll
        for (int s = 0; s < 4; ++s) {
            float x = 0.f;
            for (int hh = 0; hh < 16; ++hh) x += red[hh * 4 + s];
            v[s] = x * (1.0f / 64.0f);
        }
        float m = fmaxf(fmaxf(v[0], v[1]), fmaxf(v[2], v[3]));
        float sum = 0.f;
#pragma unroll
        for (int s = 0; s < 4; ++s) { v[s] = __expf(v[s] - m); sum += v[s]; }
#pragma unroll
        for (int s = 0; s < 4; ++s) ws[s] = v[s] / sum;
    }
    __syncthreads();
    if (t < 4) out_w[pos * 4 + t] = ws[t];
    float v = 0.f;
#pragma unroll
    for (int s = 0; s < 4; ++s) v += ws[s] * X[(size_t)(s * 256 + pos) * 256 + t];
    out_int[(size_t)pos * 256 + t] = v;
}

// =====================================================================
// k_mid: FUSED ce_int v15+depth3 (blocks 0..511) + small_int hv (512..1023).
// ce_int: barrier-free per-wave-head, M prefetch deepened to 3 bodies
// (A[4][2], ~480 cyc in-flight >= L2 latency). Dyn LDS 49152.
// =====================================================================
__global__ __launch_bounds__(512) void k_mid(const float* __restrict__ Xg32,
                                             const f16* __restrict__ MTce,
                                             float* __restrict__ acc_out,
                                             const float* __restrict__ hv,
                                             const f16* __restrict__ MThv,
                                             float* __restrict__ wpart) {
    extern __shared__ __align__(16) char smem[];
    const int t = threadIdx.x;
    const int lane = t & 63;
    const int w = t >> 6;
    const int g = lane >> 4;
    const int l15 = lane & 15;

    if (blockIdx.x < 512) {
        // ---------------- ce_int branch ----------------
        const int bg = blockIdx.x;
        {
            const float* xg = Xg32 + (size_t)bg * 64 * 384;
#pragma unroll
            for (int p = 0; p < 6; ++p) {
                int idx = p * 512 + t;
                int row = idx / 48, s = idx - row * 48;
                int c = s ^ (row & 7);
                const float* src = xg + row * 384 + c * 8;
                float4 v0 = *(const float4*)src;
                float4 v1 = *(const float4*)(src + 4);
                f16x8 o;
                o[0] = (f16)v0.x; o[1] = (f16)v0.y; o[2] = (f16)v0.z; o[3] = (f16)v0.w;
                o[4] = (f16)v1.x; o[5] = (f16)v1.y; o[6] = (f16)v1.z; o[7] = (f16)v1.w;
                *(f16x8*)(smem + idx * 16) = o;
            }
        }
        __syncthreads();

        const float scale = 0.051031036307982884f; // 1/sqrt(384)

        for (int h2 = 0; h2 < 2; ++h2) {
            const int h = h2 * 8 + w;
            const f16* mh = MTce + (size_t)h * 12 * 12288;

            f32x4 S2[2][2][2] = {};
            // depth-3 prefetch: A[4][2], buffer (c*12+kk)&3 == kk&3 (12%4==0)
            f16x8 A[4][2];
#pragma unroll
            for (int s0 = 0; s0 < 3; ++s0) {
                int nc = s0 / 12, nk = s0 % 12;
#pragma unroll
                for (int ft = 0; ft < 2; ++ft)
                    A[s0 & 3][ft] = *(const f16x8*)(mh + (size_t)nk * 12288 +
                                                    (size_t)(nc * 32 + ft * 16 + l15) * 32 + g * 8);
            }

            for (int c = 0; c < 12; ++c) {
                f32x4 acc[2][4] = {};
#pragma unroll
                for (int kk = 0; kk < 12; ++kk) {
                    {   // prefetch step + 3
                        int nc = c + (kk + 3) / 12;
                        int nk = (kk + 3) % 12;
                        if (nc > 11) { nc = 11; nk = 11; }
#pragma unroll
                        for (int ft = 0; ft < 2; ++ft)
                            A[(kk + 3) & 3][ft] =
                                *(const f16x8*)(mh + (size_t)nk * 12288 +
                                                (size_t)(nc * 32 + ft * 16 + l15) * 32 + g * 8);
                    }
                    f16x8 xb[4];
#pragma unroll
                    for (int mt = 0; mt < 4; ++mt) {
                        int row = mt * 16 + l15;
                        int ch = kk * 4 + g;
                        xb[mt] = *(const f16x8*)(smem + row * 768 + ((ch ^ (row & 7)) << 4));
                    }
                    __builtin_amdgcn_s_setprio(1);
#pragma unroll
                    for (int ft = 0; ft < 2; ++ft)
#pragma unroll
                        for (int mt = 0; mt < 4; ++mt)
                            acc[ft][mt] = MFMA16(A[kk & 3][ft], xb[mt], acc[ft][mt]);
                    __builtin_amdgcn_s_setprio(0);
                }

                f16x4 bf[2][4];
#pragma unroll
                for (int ft = 0; ft < 2; ++ft)
#pragma unroll
                    for (int mt = 0; mt < 4; ++mt) {
                        f32x4 v = acc[ft][mt];
                        f16x4 o;
                        o[0] = (f16)v[0]; o[1] = (f16)v[1]; o[2] = (f16)v[2]; o[3] = (f16)v[3];
                        bf[ft][mt] = o;
                    }

#pragma unroll
                for (int b = 0; b < 2; ++b)
#pragma unroll
                    for (int ks = 0; ks < 2; ++ks)
#pragma unroll
                        for (int it = 0; it < 2; ++it) {
                            int row = b * 32 + it * 16 + l15;
                            int ch = c * 4 + ks * 2 + (g >> 1);
                            f16x4 av = *(const f16x4*)(smem + row * 768 +
                                                       ((ch ^ (row & 7)) << 4) + 8 * (g & 1));
#pragma unroll
                            for (int lt = 0; lt < 2; ++lt)
                                S2[b][it][lt] = MFMA16K16(av, bf[ks][2 * b + lt], S2[b][it][lt]);
                        }
            }

#pragma unroll
            for (int b = 0; b < 2; ++b)
#pragma unroll
                for (int it = 0; it < 2; ++it) {
                    f32x4 sum0 = S2[b][it][0];
                    f32x4 sum1 = S2[b][it][1];
                    float cs0 = 0.f, cs1 = 0.f;
#pragma unroll
                    for (int j = 0; j < 4; ++j) {
                        float v0 = sum0[j] * scale, v1 = sum1[j] * scale;
                        float m = fmaxf(v0, v1);
                        m = fmaxf(m, __shfl_xor(m, 1));
                        m = fmaxf(m, __shfl_xor(m, 2));
                        m = fmaxf(m, __shfl_xor(m, 4));
                        m = fmaxf(m, __shfl_xor(m, 8));
                        float e0 = __expf(v0 - m), e1 = __expf(v1 - m);
                        float s = e0 + e1;
                        s += __shfl_xor(s, 1);
                        s += __shfl_xor(s, 2);
                        s += __shfl_xor(s, 4);
                        s += __shfl_xor(s, 8);
                        float inv = 1.f / s;
                        cs0 += e0 * inv;
                        cs1 += e1 * inv;
                    }
                    cs0 += __shfl_xor(cs0, 16); cs0 += __shfl_xor(cs0, 32);
                    cs1 += __shfl_xor(cs1, 16); cs1 += __shfl_xor(cs1, 32);
                    if (lane < 16) {
                        float* o = acc_out + (((size_t)h * 1024 + bg * 2 + b) * 2 + it) * 32;
                        o[l15] = cs0;
                        o[16 + l15] = cs1;
                    }
                }
        }
    } else {
        // ---------------- small_int(hv) branch (256-thr semantics) ----------------
        const int bid2 = blockIdx.x - 512;
        const int pos0 = (bid2 & 31) * 8;
        const int h = bid2 >> 5;

        f16(*Xs)[264] = (f16(*)[264])smem;                 // 16896 B
        f16(*Ts)[264] = (f16(*)[264])(smem + 16896);       // 16896 B

        if (t < 256) {
            int row = t >> 3, d0 = (t & 7) * 32;
            int s = row & 3, p = row >> 2;
            const float* gx = hv + (size_t)(s * 256 + pos0 + p) * 256 + d0;
#pragma unroll
            for (int i = 0; i < 32; i += 8) {
                float4 v0 = *(const float4*)(gx + i);
                float4 v1 = *(const float4*)(gx + i + 4);
                f16x8 o;
                o[0] = (f16)v0.x; o[1] = (f16)v0.y; o[2] = (f16)v0.z; o[3] = (f16)v0.w;
                o[4] = (f16)v1.x; o[5] = (f16)v1.y; o[6] = (f16)v1.z; o[7] = (f16)v1.w;
                *(f16x8*)&Xs[row][d0 + i] = o;
            }
        }
        __syncthreads();

        if (t < 256) {
            const f16* mh = MThv + (size_t)h * 8 * 256 * 32;
            const int fb = w * 64 + l15;
            f32x4 acc[2][4] = {};
            f16x8 bq[4], bn[4];
#pragma unroll
            for (int nt = 0; nt < 4; ++nt)
                bq[nt] = *(const f16x8*)(mh + (size_t)(fb + nt * 16) * 32 + g * 8);
#pragma unroll
            for (int kk = 0; kk < 8; ++kk) {
                if (kk < 7) {
#pragma unroll
                    for (int nt = 0; nt < 4; ++nt)
                        bn[nt] = *(const f16x8*)(mh + ((size_t)(kk + 1) * 256 + fb + nt * 16) * 32 + g * 8);
                }
                f16x8 a[2];
#pragma unroll
                for (int mt = 0; mt < 2; ++mt)
                    a[mt] = *(const f16x8*)&Xs[mt * 16 + l15][kk * 32 + g * 8];
#pragma unroll
                for (int mt = 0; mt < 2; ++mt)
#pragma unroll
                    for (int nt = 0; nt < 4; ++nt)
                        acc[mt][nt] = MFMA16(a[mt], bq[nt], acc[mt][nt]);
#pragma unroll
                for (int nt = 0; nt < 4; ++nt) bq[nt] = bn[nt];
            }
#pragma unroll
            for (int mt = 0; mt < 2; ++mt)
#pragma unroll
                for (int nt = 0; nt < 4; ++nt)
#pragma unroll
                    for (int j = 0; j < 4; ++j)
                        Ts[mt * 16 + g * 4 + j][w * 64 + nt * 16 + l15] = (f16)acc[mt][nt][j];
        }
        __syncthreads();

        if (t < 128) {
            f32x4 sacc = {};
#pragma unroll
            for (int ks = 0; ks < 8; ++ks) {
                f16x8 a = *(const f16x8*)&Ts[w * 16 + l15][ks * 32 + g * 8];
                f16x8 b = *(const f16x8*)&Xs[w * 16 + l15][ks * 32 + g * 8];
                sacc = MFMA16(a, b, sacc);
            }
            if ((l15 >> 2) == g) {
                const float scale = 1.0f / 16.0f; // 1/sqrt(256)
                float add = 0.f;
#pragma unroll
                for (int j = 0; j < 4; ++j) {
                    float v = sacc[j] * scale;
                    float m = v;
                    m = fmaxf(m, __shfl_xor(m, 1));
                    m = fmaxf(m, __shfl_xor(m, 2));
                    float e = __expf(v - m);
                    float s2 = e;
                    s2 += __shfl_xor(s2, 1);
                    s2 += __shfl_xor(s2, 2);
                    add += e / s2;
                }
                int pg = pos0 + w * 4 + g;
                wpart[((size_t)h * 256 + pg) * 4 + (l15 & 3)] = add;
            }
        }
    }
}

// =====================================================================
// k_back: FUSED ce_pool (blocks 0..1023) + small_fin hv (1024..1279).
// =====================================================================
__global__ __launch_bounds__(256) void k_back(const float* __restrict__ accp,
                                              const float* __restrict__ exv,
                                              float* __restrict__ pooled,
                                              const float* __restrict__ wpart,
                                              const float* __restrict__ hv,
                                              float* __restrict__ out_int,
                                              float* __restrict__ out_w) {
    const int t = threadIdx.x;
    __shared__ float ww[32];
    __shared__ float red[64];
    __shared__ float ws[4];

    if (blockIdx.x < 1024) {
        const int b = blockIdx.x;
        if (t < 32) {
            float s = 0.f;
#pragma unroll
            for (int h = 0; h < 16; ++h) {
                s += accp[(((size_t)h * 1024 + b) * 2 + 0) * 32 + t];
                s += accp[(((size_t)h * 1024 + b) * 2 + 1) * 32 + t];
            }
            s *= (1.0f / 512.0f);
            float m = s;
            m = fmaxf(m, __shfl_xor(m, 1));
            m = fmaxf(m, __shfl_xor(m, 2));
            m = fmaxf(m, __shfl_xor(m, 4));
            m = fmaxf(m, __shfl_xor(m, 8));
            m = fmaxf(m, __shfl_xor(m, 16));
            float e = __expf(s - m);
            float sum = e;
            sum += __shfl_xor(sum, 1);
            sum += __shfl_xor(sum, 2);
            sum += __shfl_xor(sum, 4);
            sum += __shfl_xor(sum, 8);
            sum += __shfl_xor(sum, 16);
            ww[t] = e / sum;
        }
        __syncthreads();
        for (int d = t; d < 384; d += 256) {
            float v = 0.f;
#pragma unroll
            for (int m = 0; m < 32; ++m) v += ww[m] * exv[((size_t)b * 32 + m) * 384 + d];
            pooled[(size_t)b * 384 + d] = v;
        }
    } else {
        const int pos = blockIdx.x - 1024;
        if (t < 64) red[t] = wpart[((size_t)(t >> 2) * 256 + pos) * 4 + (t & 3)];
        __syncthreads();
        if (t == 0) {
            float v[4];
#pragma unroll
            for (int s = 0; s < 4; ++s) {
                float x = 0.f;
                for (int hh = 0; hh < 16; ++hh) x += red[hh * 4 + s];
                v[s] = x * (1.0f / 64.0f);
            }
            float m = fmaxf(fmaxf(v[0], v[1]), fmaxf(v[2], v[3]));
            float sum = 0.f;
#pragma unroll
            for (int s = 0; s < 4; ++s) { v[s] = __expf(v[s] - m); sum += v[s]; }
#pragma unroll
            for (int s = 0; s < 4; ++s) ws[s] = v[s] / sum;
        }
        __syncthreads();
        if (t < 4) out_w[pos * 4 + t] = ws[t];
        float v = 0.f;
#pragma unroll
        for (int s = 0; s < 4; ++s) v += ws[s] * hv[(size_t)(s * 256 + pos) * 256 + t];
        out_int[(size_t)pos * 256 + t] = v;
    }
}

// =====================================================================
extern "C" void kernel_launch(void* const* d_in, const int* in_sizes, int n_in,
                              void* d_out, int out_size, void* d_ws, size_t ws_size,
                              hipStream_t stream) {
    const float* h_V    = (const float*)d_in[0];
    const float* h_EXV  = (const float*)d_in[1];
    const float* W_hV   = (const float*)d_in[2];
    const float* b_hV   = (const float*)d_in[3];
    const float* Wq_hv  = (const float*)d_in[4];
    const float* Wk_hv  = (const float*)d_in[5];
    const float* Wq_ce  = (const float*)d_in[6];
    const float* Wk_ce  = (const float*)d_in[7];
    const float* W_ce   = (const float*)d_in[8];
    const float* b_ce   = (const float*)d_in[9];
    const float* Wq_sce = (const float*)d_in[10];
    const float* Wk_sce = (const float*)d_in[11];
    float* out = (float*)d_out;

    char* ws = (char*)d_ws;
    f16*   mt_hv  = (f16*)(ws + 0);           //  2,097,152
    f16*   mt_sce = (f16*)(ws + 2097152);     //  2,097,152
    f16*   mt_ce  = (f16*)(ws + 4194304);     //  4,718,592
    float* hv     = (float*)(ws + 8912896);   //  1,048,576
    float* ce     = (float*)(ws + 9961472);   //  1,048,576
    float* accp   = (float*)(ws + 11010048);  //  4,194,304
    float* pooled = (float*)(ws + 15204352);  //  1,572,864
    float* wpart  = (float*)(ws + 16777216);  //     65,536

    k_front<<<1344, 256, 39936, stream>>>(Wq_hv, Wk_hv, mt_hv,
                                          Wq_ce, Wk_ce, mt_ce,
                                          Wq_sce, Wk_sce, mt_sce,
                                          h_V, W_hV, b_hV, hv);
    k_mid<<<1024, 512, 49152, stream>>>(h_EXV, mt_ce, accp, hv, mt_hv, wpart);
    k_back<<<1280, 256, 0, stream>>>(accp, h_EXV, pooled, wpart, hv,
                                     out + 0, out + 65536);
    k_lin<<<256, 256, 0, stream>>>(pooled, W_ce, b_ce, ce, 384);
    k_small_int<<<dim3(32, 16), 256, 0, stream>>>(ce, mt_sce, wpart);
    k_small_fin<<<256, 256, 0, stream>>>(wpart, ce, out + 66560, out + 132096);
}